// Round 7
// baseline (47.047 us; speedup 1.0000x reference)
//
#include <hip/hip_runtime.h>

#define S_DIM 4096
#define B_DIM 8
#define LN_EPS 1e-3f

typedef _Float16 half8 __attribute__((ext_vector_type(8)));
typedef _Float16 half2v __attribute__((ext_vector_type(2)));
typedef float f32x4 __attribute__((ext_vector_type(4)));

// ---------------------------------------------------------------------------
// Prep: Wt[a][k][c] = (f16) W[k][a][c]
// ---------------------------------------------------------------------------
__global__ __launch_bounds__(256) void prep_wt(const float* __restrict__ W,
                                               _Float16* __restrict__ wt) {
    int idx = blockIdx.x * 256 + threadIdx.x;   // [a][k][c], c fastest
    int a = idx >> 12;
    int k = (idx >> 6) & 63;
    int c = idx & 63;
    wt[idx] = (_Float16)W[((k << 6) + a) * 64 + c];
}

// ---------------------------------------------------------------------------
// Fused kernel: per 64-row tile —
//   Phase A (banded s_pre): 3 j-tiles via MFMA, s kept in LDS (no HBM trip).
//   Phase B (bilinear GEMM): K-split 4 waves, R=4 row-tiles; W fragments
//     loaded DIRECT to VGPRs (no LDS, no barriers, no waitcnt asm),
//     double-buffered at half-iteration granularity.
//   Epilogue: f16 partial dump in acc-layout (lane-contiguous), wave 0
//     combines + residual + LayerNorm.
//   LDS 33.8KB, ~155 VGPR -> 3 blocks/CU (12 waves/CU).
// ---------------------------------------------------------------------------
__global__ __launch_bounds__(256, 3) void fused(const float* __restrict__ x,
                                                const _Float16* __restrict__ wt,
                                                const float* __restrict__ gamma,
                                                const float* __restrict__ beta,
                                                float* __restrict__ out) {
    const int r0g = blockIdx.x * 64;         // flattened B*S row
    const int by  = r0g >> 12;
    const int it  = (r0g & 4095) >> 6;
    const int i0  = it * 64;
    const int tid = threadIdx.x;
    const int w = tid >> 6, l = tid & 63, lg = l >> 4, lr = l & 15;

    __shared__ __align__(16) char smem[9216 + 24576];
    _Float16* Bs = (_Float16*)smem;            // [c][j] stride 72: x f16 (lives through phase B)
    _Float16* sS = (_Float16*)(smem + 9216);   // [row][c] stride 72 (dead after sf read)
    half2v*   Pf = (half2v*)(smem + 9216);     // 3 x [rt][nt][pair][64] f16 partials (overlay)

    // ================= Phase A: banded s_pre =================
    f32x4 accA[4] = {};
    {
        const float iRowF = (float)(i0 + w * 16 + lr);
        const int ldC = tid & 63;
        const int ldJ = (tid >> 6) * 16;
        const int jt0 = (it >= 2) ? (it - 2) : 0;
        for (int jt = jt0; jt <= it; ++jt) {
            const int j0 = jt * 64;
            __syncthreads();
            {
                const float* xp = x + ((size_t)by * S_DIM + j0 + ldJ) * 64 + ldC;
                half8 v0, v1;
                #pragma unroll
                for (int q = 0; q < 8; ++q) {
                    v0[q] = (_Float16)xp[q * 64];
                    v1[q] = (_Float16)xp[(8 + q) * 64];
                }
                *(half8*)&Bs[ldC * 72 + ldJ] = v0;
                *(half8*)&Bs[ldC * 72 + ldJ + 8] = v1;
            }
            __syncthreads();
            #pragma unroll
            for (int kk = 0; kk < 2; ++kk) {
                half8 af;
                #pragma unroll
                for (int bq = 0; bq < 8; ++bq) {
                    int j = j0 + kk * 32 + lg * 8 + bq;
                    float df = iRowF - (float)j;
                    float tv = (df > 0.f) ? __builtin_amdgcn_rcpf(df * df) : 0.f;
                    af[bq] = (_Float16)tv;
                }
                #pragma unroll
                for (int nt = 0; nt < 4; ++nt) {
                    half8 bf_ = *(const half8*)&Bs[(nt * 16 + lr) * 72 + kk * 32 + lg * 8];
                    accA[nt] = __builtin_amdgcn_mfma_f32_16x16x32_f16(af, bf_, accA[nt], 0, 0, 0);
                }
            }
        }
        // after the loop, Bs holds x[r0..r0+64) f16 transposed -> xa table for phase B
    }
    // write s to LDS (D layout: col=lr, row=lg*4+r), then re-read as A-fragments
    #pragma unroll
    for (int nt = 0; nt < 4; ++nt)
        #pragma unroll
        for (int r = 0; r < 4; ++r)
            sS[(w * 16 + lg * 4 + r) * 72 + nt * 16 + lr] = (_Float16)accA[nt][r];
    __syncthreads();

    half8 sf[4][2];
    #pragma unroll
    for (int rt = 0; rt < 4; ++rt) {
        sf[rt][0] = *(const half8*)&sS[(rt * 16 + lr) * 72 + lg * 8];
        sf[rt][1] = *(const half8*)&sS[(rt * 16 + lr) * 72 + 32 + lg * 8];
    }

    // ================= Phase B: bilinear GEMM, no barriers =================
    // wave w owns a = w*16 + t (t 0..15). Fragment (nt, j): row k = nt*16+lr,
    // cols c = j*32 + lg*8.  Direct global loads, double-buffered per half.
    const char* wlane = (const char*)wt + ((size_t)w << 17) + lr * 128 + lg * 16;

    half8 bf[2][2][2];   // [half-slot][ntLocal][j]
    f32x4 acc[4][4] = {};

#define LOADS(t_, h_)                                                          \
    {                                                                          \
        _Pragma("unroll")                                                      \
        for (int n_ = 0; n_ < 2; ++n_)                                         \
            _Pragma("unroll")                                                  \
            for (int j_ = 0; j_ < 2; ++j_)                                     \
                bf[h_][n_][j_] = *(const half8*)(wlane + (t_) * 8192 +         \
                                   ((h_) * 2 + n_) * 2048 + j_ * 64);          \
    }
#define COMPUTE(h_)                                                            \
    {                                                                          \
        _Pragma("unroll")                                                      \
        for (int rt_ = 0; rt_ < 4; ++rt_) {                                    \
            half8 a0 = sf[rt_][0] * xa[rt_];                                   \
            half8 a1 = sf[rt_][1] * xa[rt_];                                   \
            _Pragma("unroll")                                                  \
            for (int n_ = 0; n_ < 2; ++n_) {                                   \
                acc[rt_][(h_) * 2 + n_] = __builtin_amdgcn_mfma_f32_16x16x32_f16( \
                    a0, bf[h_][n_][0], acc[rt_][(h_) * 2 + n_], 0, 0, 0);      \
                acc[rt_][(h_) * 2 + n_] = __builtin_amdgcn_mfma_f32_16x16x32_f16( \
                    a1, bf[h_][n_][1], acc[rt_][(h_) * 2 + n_], 0, 0, 0);      \
            }                                                                  \
        }                                                                      \
    }

    LOADS(0, 0);
    #pragma unroll
    for (int t = 0; t < 16; ++t) {
        _Float16 xa[4];
        #pragma unroll
        for (int rt = 0; rt < 4; ++rt)
            xa[rt] = Bs[(w * 16 + t) * 72 + rt * 16 + lr];
        // half 0: prefetch half 1 of this t, compute nt 0,1
        LOADS(t, 1);
        COMPUTE(0);
        // half 1: prefetch half 0 of t+1, compute nt 2,3
        if (t < 15) LOADS(t + 1, 0);
        COMPUTE(1);
    }
#undef LOADS
#undef COMPUTE

    // ================= Epilogue =================
    __syncthreads();                      // everyone past sS reads; loop done
    if (w != 0) {                         // dump partials in acc layout (f16)
        const int ph = w - 1;
        #pragma unroll
        for (int rt = 0; rt < 4; ++rt)
            #pragma unroll
            for (int nt = 0; nt < 4; ++nt) {
                int base = (((ph * 4 + rt) * 4 + nt) * 2) * 64 + l;
                half2v p01 = { (_Float16)acc[rt][nt][0], (_Float16)acc[rt][nt][1] };
                half2v p23 = { (_Float16)acc[rt][nt][2], (_Float16)acc[rt][nt][3] };
                Pf[base] = p01;
                Pf[base + 64] = p23;
            }
    }
    __syncthreads();

    if (w == 0) {
        float gba[4], bta[4];
        #pragma unroll
        for (int nt = 0; nt < 4; ++nt) {
            gba[nt] = gamma[nt * 16 + lr];
            bta[nt] = beta[nt * 16 + lr];
        }
        #pragma unroll
        for (int rt = 0; rt < 4; ++rt) {
            float rv[4][4], sum[4], ssq[4];
            // combine partials (lane-contiguous reads)
            #pragma unroll
            for (int nt = 0; nt < 4; ++nt) {
                float v0 = acc[rt][nt][0], v1 = acc[rt][nt][1];
                float v2 = acc[rt][nt][2], v3 = acc[rt][nt][3];
                #pragma unroll
                for (int ph = 0; ph < 3; ++ph) {
                    int base = (((ph * 4 + rt) * 4 + nt) * 2) * 64 + l;
                    half2v q01 = Pf[base];
                    half2v q23 = Pf[base + 64];
                    v0 += (float)q01[0]; v1 += (float)q01[1];
                    v2 += (float)q23[0]; v3 += (float)q23[1];
                }
                acc[rt][nt][0] = v0; acc[rt][nt][1] = v1;
                acc[rt][nt][2] = v2; acc[rt][nt][3] = v3;
            }
            #pragma unroll
            for (int reg = 0; reg < 4; ++reg) {
                const int row_l = rt * 16 + lg * 4 + reg;
                const float* xr = x + (size_t)(r0g + row_l) * 64;
                float s_ = 0.f, q_ = 0.f;
                #pragma unroll
                for (int nt = 0; nt < 4; ++nt) {
                    float v = acc[rt][nt][reg] + xr[nt * 16 + lr];
                    rv[nt][reg] = v;
                    s_ += v;
                    q_ += v * v;
                }
                sum[reg] = s_;
                ssq[reg] = q_;
            }
            #pragma unroll
            for (int m = 1; m < 16; m <<= 1) {
                #pragma unroll
                for (int reg = 0; reg < 4; ++reg) {
                    sum[reg] += __shfl_xor(sum[reg], m, 64);
                    ssq[reg] += __shfl_xor(ssq[reg], m, 64);
                }
            }
            #pragma unroll
            for (int reg = 0; reg < 4; ++reg) {
                float mean = sum[reg] * (1.f / 64.f);
                float var = ssq[reg] * (1.f / 64.f) - mean * mean;
                float rstd = __frsqrt_rn(var + LN_EPS);
                const int gr = r0g + rt * 16 + lg * 4 + reg;
                #pragma unroll
                for (int nt = 0; nt < 4; ++nt) {
                    float y = (rv[nt][reg] - mean) * rstd * gba[nt] + bta[nt];
                    out[(size_t)gr * 64 + nt * 16 + lr] = y;
                }
            }
        }
    }
}

// ---------------------------------------------------------------------------
extern "C" void kernel_launch(void* const* d_in, const int* in_sizes, int n_in,
                              void* d_out, int out_size, void* d_ws, size_t ws_size,
                              hipStream_t stream) {
    const float* x     = (const float*)d_in[0];
    const float* W     = (const float*)d_in[1];
    const float* gamma = (const float*)d_in[2];
    const float* beta  = (const float*)d_in[3];
    float* outp        = (float*)d_out;

    _Float16* wt = (_Float16*)d_ws;   // 512 KB f16 [a][k][c]

    prep_wt<<<1024, 256, 0, stream>>>(W, wt);
    fused<<<(B_DIM * S_DIM) / 64, 256, 0, stream>>>(x, wt, gamma, beta, outp);
}

// Round 8
// 44.425 us; speedup vs baseline: 1.0590x; 1.0590x over previous
//
#include <hip/hip_runtime.h>

#define S_DIM 4096
#define B_DIM 8
#define LN_EPS 1e-3f

typedef _Float16 half8 __attribute__((ext_vector_type(8)));
typedef _Float16 half2v __attribute__((ext_vector_type(2)));
typedef float f32x4 __attribute__((ext_vector_type(4)));

__device__ __forceinline__ void async_copy16(void* lds, const void* gsrc) {
    __builtin_amdgcn_global_load_lds(
        (const __attribute__((address_space(1))) unsigned int*)gsrc,
        (__attribute__((address_space(3))) unsigned int*)lds, 16, 0, 0);
}

// ---------------------------------------------------------------------------
// Fused: blocks 0..511 = stage1 (banded s_pre, MFMA); 512..1535 = W transpose.
// stage1 first so the critical path (s_pre -> stage2) starts immediately.
// ---------------------------------------------------------------------------
__global__ __launch_bounds__(256) void prep_stage1(const float* __restrict__ x,
                                                   const float* __restrict__ W,
                                                   _Float16* __restrict__ wt,
                                                   _Float16* __restrict__ s_out) {
    if (blockIdx.x >= 512) {   // ---- prep role: Wt[a][k][c] = W[k][a][c] ----
        int idx = (blockIdx.x - 512) * 256 + threadIdx.x;
        int a = idx >> 12;
        int k = (idx >> 6) & 63;
        int c = idx & 63;
        wt[idx] = (_Float16)W[((k << 6) + a) * 64 + c];
        return;
    }
    // ---- stage1 role: banded s_pre (d <= 128..192) ----
    const int lin = blockIdx.x;
    const int it = lin & 63;
    const int by = lin >> 6;
    const int i0 = it * 64;
    const int tid = threadIdx.x;
    const int w = tid >> 6, l = tid & 63, lg = l >> 4, lr = l & 15;

    __shared__ _Float16 Bs[64 * 72];

    f32x4 acc[4] = {};
    const float iRowF = (float)(i0 + w * 16 + lr);
    const int ldC = tid & 63;
    const int ldJ = (tid >> 6) * 16;

    const int jt0 = (it >= 2) ? (it - 2) : 0;
    for (int jt = jt0; jt <= it; ++jt) {
        const int j0 = jt * 64;
        __syncthreads();
        {
            const float* xp = x + ((size_t)by * S_DIM + j0 + ldJ) * 64 + ldC;
            half8 v0, v1;
            #pragma unroll
            for (int q = 0; q < 8; ++q) {
                v0[q] = (_Float16)xp[q * 64];
                v1[q] = (_Float16)xp[(8 + q) * 64];
            }
            *(half8*)&Bs[ldC * 72 + ldJ] = v0;
            *(half8*)&Bs[ldC * 72 + ldJ + 8] = v1;
        }
        __syncthreads();
        #pragma unroll
        for (int kk = 0; kk < 2; ++kk) {
            half8 af;
            #pragma unroll
            for (int bq = 0; bq < 8; ++bq) {
                int j = j0 + kk * 32 + lg * 8 + bq;
                float df = iRowF - (float)j;
                float tv = (df > 0.f) ? __builtin_amdgcn_rcpf(df * df) : 0.f;
                af[bq] = (_Float16)tv;
            }
            #pragma unroll
            for (int nt = 0; nt < 4; ++nt) {
                half8 bf = *(const half8*)&Bs[(nt * 16 + lr) * 72 + kk * 32 + lg * 8];
                acc[nt] = __builtin_amdgcn_mfma_f32_16x16x32_f16(af, bf, acc[nt], 0, 0, 0);
            }
        }
    }

    #pragma unroll
    for (int nt = 0; nt < 4; ++nt) {
        #pragma unroll
        for (int r = 0; r < 4; ++r) {
            int i = i0 + w * 16 + lg * 4 + r;
            int c = nt * 16 + lr;
            s_out[((size_t)by * S_DIM + i) * 64 + c] = (_Float16)acc[nt][r];
        }
    }
}

// ---------------------------------------------------------------------------
// Stage 2 v6: 512 thr / 8 waves / 64 rows, K-SPLIT 8 (wave w: a = w*8+t).
//   Wave-private 2x4KB half-slice double buffers (barrier-free K-loop,
//   counted vmcnt(4)). s-fragments re-read from LDS each half-step (register
//   diet -> 4 waves/SIMD, 2 blocks/CU). T5 setprio around MFMA cluster.
// ---------------------------------------------------------------------------
__global__ __launch_bounds__(512, 4) void stage2(const float* __restrict__ x,
                                                 const _Float16* __restrict__ s,
                                                 const _Float16* __restrict__ wt,
                                                 const float* __restrict__ gamma,
                                                 const float* __restrict__ beta,
                                                 float* __restrict__ out) {
    const int r0 = blockIdx.x * 64;
    const int tid = threadIdx.x;
    const int w = tid >> 6, l = tid & 63, lg = l >> 4, lr = l & 15;

    __shared__ __align__(16) char smem[65536 + 9216];   // 73 KB
    char* myBuf = smem + w * 8192;                 // wave-private 2 x 4KB
    _Float16* sS = (_Float16*)(smem + 65536);      // [64][72] s tile
    half2v* Pf = (half2v*)smem;                    // epilogue partials (overlay)

    // source pre-swizzle (involution): LDS[row][slot] <- G[row][slot ^ (row&7)]
    const int laneSrc = ((l >> 3) * 128) + ((((l & 7) ^ (l >> 3)) << 4));
    const char* wbase = (const char*)wt + (size_t)w * 8 * 8192;   // slices w*8..

    // half-step hs = t*2 + h: 4KB = k rows h*32..h*32+31 of slice t
#define STAGEH(hs_, buf_)                                                      \
    {                                                                          \
        _Pragma("unroll")                                                      \
        for (int b_ = 0; b_ < 4; ++b_)                                         \
            async_copy16(myBuf + (buf_) * 4096 + b_ * 1024,                    \
                         wbase + (size_t)(hs_) * 4096 + b_ * 1024 + laneSrc);  \
    }

    STAGEH(0, 0);
    STAGEH(1, 1);

    {   // stage sS: 64 rows x 64 c f16, stride 72 (2-way max on frag reads)
        int row = tid >> 3, c0 = (tid & 7) * 8;
        half8 sv = *(const half8*)&s[(size_t)(r0 + row) * 64 + c0];
        *(half8*)&sS[row * 72 + c0] = sv;
    }

    // xa scalars: x[r0 + rt*16+lr][w*8 .. w*8+7] as f16 (16 VGPR)
    half8 xav[4];
    #pragma unroll
    for (int rt = 0; rt < 4; ++rt) {
        const float* xp = x + (size_t)(r0 + rt * 16 + lr) * 64 + w * 8;
        float4 v0 = *(const float4*)xp;
        float4 v1 = *(const float4*)(xp + 4);
        half8 h;
        h[0] = (_Float16)v0.x; h[1] = (_Float16)v0.y;
        h[2] = (_Float16)v0.z; h[3] = (_Float16)v0.w;
        h[4] = (_Float16)v1.x; h[5] = (_Float16)v1.y;
        h[6] = (_Float16)v1.z; h[7] = (_Float16)v1.w;
        xav[rt] = h;
    }

    __syncthreads();   // sS visible; prologue vmcnt drained by barrier semantics

    f32x4 acc[4][4] = {};
    const int swz0 = (lg * 16) ^ ((lr & 7) << 4);
    const int swz1 = (64 + lg * 16) ^ ((lr & 7) << 4);

    #pragma unroll
    for (int hs = 0; hs < 16; ++hs) {
        const int h = hs & 1;                      // k-half (== buffer parity)
        const char* wa = myBuf + h * 4096;
        // B fragments: rows (ntl*16+lr) of this k-half, swizzled
        const char* rp0 = wa + lr * 128;
        const char* rp1 = wa + (16 + lr) * 128;
        half8 b00 = *(const half8*)(rp0 + swz0);
        half8 b01 = *(const half8*)(rp0 + swz1);
        half8 b10 = *(const half8*)(rp1 + swz0);
        half8 b11 = *(const half8*)(rp1 + swz1);

        __builtin_amdgcn_s_setprio(1);
        #pragma unroll
        for (int rt = 0; rt < 4; ++rt) {
            _Float16 xa = xav[rt][hs >> 1];
            half8 s0 = *(const half8*)&sS[(rt * 16 + lr) * 72 + lg * 8];
            half8 s1 = *(const half8*)&sS[(rt * 16 + lr) * 72 + 32 + lg * 8];
            half8 a0 = s0 * xa;
            half8 a1 = s1 * xa;
            acc[rt][h * 2 + 0] = __builtin_amdgcn_mfma_f32_16x16x32_f16(a0, b00, acc[rt][h * 2 + 0], 0, 0, 0);
            acc[rt][h * 2 + 0] = __builtin_amdgcn_mfma_f32_16x16x32_f16(a1, b01, acc[rt][h * 2 + 0], 0, 0, 0);
            acc[rt][h * 2 + 1] = __builtin_amdgcn_mfma_f32_16x16x32_f16(a0, b10, acc[rt][h * 2 + 1], 0, 0, 0);
            acc[rt][h * 2 + 1] = __builtin_amdgcn_mfma_f32_16x16x32_f16(a1, b11, acc[rt][h * 2 + 1], 0, 0, 0);
        }
        __builtin_amdgcn_s_setprio(0);

        if (hs < 14) {
            __builtin_amdgcn_sched_barrier(0);
            STAGEH(hs + 2, h);                     // refill just-consumed buffer
            asm volatile("s_waitcnt vmcnt(4)" ::: "memory");   // hs+1 resident
            __builtin_amdgcn_sched_barrier(0);
        } else if (hs == 14) {
            asm volatile("s_waitcnt vmcnt(0)" ::: "memory");   // hs 15 resident
            __builtin_amdgcn_sched_barrier(0);
        }
    }
#undef STAGEH

    // ---- epilogue: waves 1..7 dump f16 partials (lane-contiguous), wave 0
    //      combines + residual + LayerNorm ----
    __syncthreads();                               // staging buffers now dead
    if (w != 0) {
        const int ph = w - 1;                      // 0..6
        #pragma unroll
        for (int rt = 0; rt < 4; ++rt)
            #pragma unroll
            for (int nt = 0; nt < 4; ++nt) {
                int base = (((ph * 4 + rt) * 4 + nt) * 2) * 64 + l;
                half2v p01 = { (_Float16)acc[rt][nt][0], (_Float16)acc[rt][nt][1] };
                half2v p23 = { (_Float16)acc[rt][nt][2], (_Float16)acc[rt][nt][3] };
                Pf[base] = p01;
                Pf[base + 64] = p23;
            }
    }
    __syncthreads();

    if (w == 0) {
        float gba[4], bta[4];
        #pragma unroll
        for (int nt = 0; nt < 4; ++nt) {
            gba[nt] = gamma[nt * 16 + lr];
            bta[nt] = beta[nt * 16 + lr];
        }
        #pragma unroll
        for (int rt = 0; rt < 4; ++rt) {
            float rv[4][4], sum[4], ssq[4];
            #pragma unroll
            for (int nt = 0; nt < 4; ++nt) {
                float v0 = acc[rt][nt][0], v1 = acc[rt][nt][1];
                float v2 = acc[rt][nt][2], v3 = acc[rt][nt][3];
                #pragma unroll
                for (int ph = 0; ph < 7; ++ph) {
                    int base = (((ph * 4 + rt) * 4 + nt) * 2) * 64 + l;
                    half2v q01 = Pf[base];
                    half2v q23 = Pf[base + 64];
                    v0 += (float)q01[0]; v1 += (float)q01[1];
                    v2 += (float)q23[0]; v3 += (float)q23[1];
                }
                acc[rt][nt][0] = v0; acc[rt][nt][1] = v1;
                acc[rt][nt][2] = v2; acc[rt][nt][3] = v3;
            }
            #pragma unroll
            for (int reg = 0; reg < 4; ++reg) {
                const int row_l = rt * 16 + lg * 4 + reg;
                const float* xr = x + (size_t)(r0 + row_l) * 64;
                float s_ = 0.f, q_ = 0.f;
                #pragma unroll
                for (int nt = 0; nt < 4; ++nt) {
                    float v = acc[rt][nt][reg] + xr[nt * 16 + lr];
                    rv[nt][reg] = v;
                    s_ += v;
                    q_ += v * v;
                }
                sum[reg] = s_;
                ssq[reg] = q_;
            }
            #pragma unroll
            for (int m = 1; m < 16; m <<= 1) {
                #pragma unroll
                for (int reg = 0; reg < 4; ++reg) {
                    sum[reg] += __shfl_xor(sum[reg], m, 64);
                    ssq[reg] += __shfl_xor(ssq[reg], m, 64);
                }
            }
            #pragma unroll
            for (int reg = 0; reg < 4; ++reg) {
                float mean = sum[reg] * (1.f / 64.f);
                float var = ssq[reg] * (1.f / 64.f) - mean * mean;
                float rstd = __frsqrt_rn(var + LN_EPS);
                const int gr = r0 + rt * 16 + lg * 4 + reg;
                #pragma unroll
                for (int nt = 0; nt < 4; ++nt) {
                    float y = (rv[nt][reg] - mean) * rstd * gba[nt] + bta[nt];
                    out[(size_t)gr * 64 + nt * 16 + lr] = y;
                }
            }
        }
    }
}

// ---------------------------------------------------------------------------
extern "C" void kernel_launch(void* const* d_in, const int* in_sizes, int n_in,
                              void* d_out, int out_size, void* d_ws, size_t ws_size,
                              hipStream_t stream) {
    const float* x     = (const float*)d_in[0];
    const float* W     = (const float*)d_in[1];
    const float* gamma = (const float*)d_in[2];
    const float* beta  = (const float*)d_in[3];
    float* outp        = (float*)d_out;

    char* ws = (char*)d_ws;
    _Float16* s_f16 = (_Float16*)ws;                                  // 4 MB
    _Float16* wt    = (_Float16*)(ws + (size_t)B_DIM * S_DIM * 64 * 2); // 512 KB

    prep_stage1<<<1536, 256, 0, stream>>>(x, W, wt, s_f16);
    stage2<<<(B_DIM * S_DIM) / 64, 512, 0, stream>>>(x, s_f16, wt, gamma, beta, outp);
}

// Round 9
// 37.774 us; speedup vs baseline: 1.2455x; 1.1761x over previous
//
#include <hip/hip_runtime.h>

#define S_DIM 4096
#define B_DIM 8
#define LN_EPS 1e-3f

typedef _Float16 half8 __attribute__((ext_vector_type(8)));
typedef _Float16 half2v __attribute__((ext_vector_type(2)));
typedef float f32x4 __attribute__((ext_vector_type(4)));

__device__ __forceinline__ void async_copy16(void* lds, const void* gsrc) {
    __builtin_amdgcn_global_load_lds(
        (const __attribute__((address_space(1))) unsigned int*)gsrc,
        (__attribute__((address_space(3))) unsigned int*)lds, 16, 0, 0);
}

// ---------------------------------------------------------------------------
// Dispatch 1: blocks 0..511 = banded stage1 (ONE barrier); 512..1535 = prep.
// ---------------------------------------------------------------------------
__global__ __launch_bounds__(256) void prep_stage1(const float* __restrict__ x,
                                                   const float* __restrict__ W,
                                                   _Float16* __restrict__ wt,
                                                   _Float16* __restrict__ s_out) {
    if (blockIdx.x >= 512) {   // ---- prep role: Wt[a][k][c] = W[k][a][c] ----
        int idx = (blockIdx.x - 512) * 256 + threadIdx.x;
        int a = idx >> 12;
        int k = (idx >> 6) & 63;
        int c = idx & 63;
        wt[idx] = (_Float16)W[((k << 6) + a) * 64 + c];
        return;
    }
    // ---- stage1: s_pre[i,c] = sum_{d<=128..192} x[i-d,c]/d^2, one barrier ----
    const int lin = blockIdx.x;
    const int it = lin & 63;
    const int by = lin >> 6;
    const int i0 = it * 64;
    const int tid = threadIdx.x;
    const int w = tid >> 6, l = tid & 63, lg = l >> 4, lr = l & 15;

    __shared__ _Float16 Bs[64 * 200];            // [c][j], whole band (<=192 j)

    const int j0base = (it >= 2) ? (i0 - 128) : 0;
    const int nr = i0 + 64 - j0base;             // 64 / 128 / 192
    const int nk = nr >> 5;                      // 2 / 4 / 6 MFMA k-steps

    {   // load entire band once: lane = c, wave covers 48 j-rows
        const int ldC = tid & 63;
        const int jw = (tid >> 6) * 48;
        #pragma unroll
        for (int q8 = 0; q8 < 6; ++q8) {
            int jloc = jw + q8 * 8;
            if (jloc < nr) {
                const float* xp = x + ((size_t)by * S_DIM + j0base + jloc) * 64 + ldC;
                half8 v;
                #pragma unroll
                for (int q = 0; q < 8; ++q) v[q] = (_Float16)xp[q * 64];
                *(half8*)&Bs[ldC * 200 + jloc] = v;
            }
        }
    }
    __syncthreads();

    f32x4 acc[4] = {};
    const float iRowF = (float)(i0 + w * 16 + lr);
    for (int kk = 0; kk < nk; ++kk) {
        half8 af;
        #pragma unroll
        for (int bq = 0; bq < 8; ++bq) {
            int j = j0base + kk * 32 + lg * 8 + bq;
            float df = iRowF - (float)j;
            float tv = (df > 0.f) ? __builtin_amdgcn_rcpf(df * df) : 0.f;
            af[bq] = (_Float16)tv;
        }
        #pragma unroll
        for (int nt = 0; nt < 4; ++nt) {
            half8 bf = *(const half8*)&Bs[(nt * 16 + lr) * 200 + kk * 32 + lg * 8];
            acc[nt] = __builtin_amdgcn_mfma_f32_16x16x32_f16(af, bf, acc[nt], 0, 0, 0);
        }
    }

    #pragma unroll
    for (int nt = 0; nt < 4; ++nt)
        #pragma unroll
        for (int r = 0; r < 4; ++r)
            s_out[((size_t)by * S_DIM + i0 + w * 16 + lg * 4 + r) * 64 + nt * 16 + lr]
                = (_Float16)acc[nt][r];
}

// ---------------------------------------------------------------------------
// Stage 2 v7 (= v5 + early refill + pure-reg MFMA cluster + setprio):
//   64 rows/block, 4 waves, K-split 4, wave-private 2x8KB double buffer,
//   barrier-free K-loop. Per iter: 8 ds_read -> lgkm(0) -> STAGE(t+2) ->
//   [setprio] 32 MFMA [setprio] -> vmcnt(8). Prefetch distance ~1.6 iters.
// ---------------------------------------------------------------------------
__global__ __launch_bounds__(256, 2) void stage2(const float* __restrict__ x,
                                                 const _Float16* __restrict__ s,
                                                 const _Float16* __restrict__ wt,
                                                 const float* __restrict__ gamma,
                                                 const float* __restrict__ beta,
                                                 float* __restrict__ out) {
    const int r0 = blockIdx.x * 64;
    const int tid = threadIdx.x;
    const int w = tid >> 6, l = tid & 63, lg = l >> 4, lr = l & 15;

    __shared__ __align__(16) char smem[65536];
    char* myBuf = smem + w * 16384;                 // wave-private 2 x 8KB
    half2v* Pf = (half2v*)smem;                     // epilogue overlay

    // source pre-swizzle (involution): LDS[row][slot] <- G[row][slot ^ (row&7)]
    const int laneSrc = ((l >> 3) * 128) + ((((l & 7) ^ (l >> 3)) << 4));
    const char* wbase = (const char*)wt + (size_t)w * 16 * 8192;  // slices w*16..

#define STAGEW(t_, buf_)                                                       \
    {                                                                          \
        _Pragma("unroll")                                                      \
        for (int s_ = 0; s_ < 8; ++s_)                                         \
            async_copy16(myBuf + (buf_) * 8192 + s_ * 1024,                    \
                         wbase + (size_t)(t_) * 8192 + s_ * 1024 + laneSrc);   \
    }

    // register operands first (prologue drains all VMEM afterwards)
    half8 sf[4][2];
    #pragma unroll
    for (int rt = 0; rt < 4; ++rt) {
        size_t row = (size_t)(r0 + rt * 16 + lr) * 64;
        sf[rt][0] = *(const half8*)&s[row + lg * 8];
        sf[rt][1] = *(const half8*)&s[row + 32 + lg * 8];
    }
    half8 xav[4][2];
    #pragma unroll
    for (int rt = 0; rt < 4; ++rt) {
        const float* xp = x + (size_t)(r0 + rt * 16 + lr) * 64 + w * 16;
        half8 h0, h1;
        #pragma unroll
        for (int j = 0; j < 8; ++j) {
            h0[j] = (_Float16)xp[j];
            h1[j] = (_Float16)xp[8 + j];
        }
        xav[rt][0] = h0;
        xav[rt][1] = h1;
    }

    __builtin_amdgcn_sched_barrier(0);
    STAGEW(0, 0);
    STAGEW(1, 1);
    __builtin_amdgcn_sched_barrier(0);
    asm volatile("s_waitcnt vmcnt(0)" ::: "memory");
    __builtin_amdgcn_sched_barrier(0);

    f32x4 acc[4][4] = {};
    const int swz0 = (lg * 16) ^ ((lr & 7) << 4);
    const int swz1 = (64 + lg * 16) ^ ((lr & 7) << 4);

    #pragma unroll
    for (int t = 0; t < 16; ++t) {
        const char* wa = myBuf + (t & 1) * 8192;
        // 1) all b-fragments of slice t -> registers
        half8 b[4][2];
        #pragma unroll
        for (int nt = 0; nt < 4; ++nt) {
            const char* rp = wa + (nt * 16 + lr) * 128;
            b[nt][0] = *(const half8*)(rp + swz0);
            b[nt][1] = *(const half8*)(rp + swz1);
        }
        // 2) buffer (t&1) now dead -> refill it EARLY (distance ~1.6 iters)
        asm volatile("s_waitcnt lgkmcnt(0)" ::: "memory");
        __builtin_amdgcn_sched_barrier(0);
        if (t + 2 < 16) STAGEW(t + 2, t & 1);
        __builtin_amdgcn_sched_barrier(0);
        // 3) pure-register MFMA cluster
        __builtin_amdgcn_s_setprio(1);
        #pragma unroll
        for (int rt = 0; rt < 4; ++rt) {
            _Float16 xa = xav[rt][t >> 3][t & 7];
            half8 af0 = sf[rt][0] * xa;
            half8 af1 = sf[rt][1] * xa;
            #pragma unroll
            for (int nt = 0; nt < 4; ++nt) {
                acc[rt][nt] = __builtin_amdgcn_mfma_f32_16x16x32_f16(af0, b[nt][0], acc[rt][nt], 0, 0, 0);
                acc[rt][nt] = __builtin_amdgcn_mfma_f32_16x16x32_f16(af1, b[nt][1], acc[rt][nt], 0, 0, 0);
            }
        }
        __builtin_amdgcn_s_setprio(0);
        // 4) slice t+1 must be resident before next iter's ds_reads
        if (t < 14) {
            asm volatile("s_waitcnt vmcnt(8)" ::: "memory");
            __builtin_amdgcn_sched_barrier(0);
        } else if (t == 14) {
            asm volatile("s_waitcnt vmcnt(0)" ::: "memory");
            __builtin_amdgcn_sched_barrier(0);
        }
    }
#undef STAGEW

    // ---- epilogue: waves 1..3 dump f16 partials, wave 0 combines + LN ----
    __syncthreads();
    if (w != 0) {
        const int ph = w - 1;
        #pragma unroll
        for (int rt = 0; rt < 4; ++rt)
            #pragma unroll
            for (int nt = 0; nt < 4; ++nt) {
                int base = (((ph * 4 + rt) * 4 + nt) * 2) * 64 + l;
                half2v p01 = { (_Float16)acc[rt][nt][0], (_Float16)acc[rt][nt][1] };
                half2v p23 = { (_Float16)acc[rt][nt][2], (_Float16)acc[rt][nt][3] };
                Pf[base] = p01;
                Pf[base + 64] = p23;
            }
    }
    __syncthreads();

    if (w == 0) {
        float gba[4], bta[4];
        #pragma unroll
        for (int nt = 0; nt < 4; ++nt) {
            gba[nt] = gamma[nt * 16 + lr];
            bta[nt] = beta[nt * 16 + lr];
        }
        #pragma unroll
        for (int rt = 0; rt < 4; ++rt) {
            float rv[4][4], sum[4], ssq[4];
            #pragma unroll
            for (int nt = 0; nt < 4; ++nt) {
                float v0 = acc[rt][nt][0], v1 = acc[rt][nt][1];
                float v2 = acc[rt][nt][2], v3 = acc[rt][nt][3];
                #pragma unroll
                for (int ph = 0; ph < 3; ++ph) {
                    int base = (((ph * 4 + rt) * 4 + nt) * 2) * 64 + l;
                    half2v q01 = Pf[base];
                    half2v q23 = Pf[base + 64];
                    v0 += (float)q01[0]; v1 += (float)q01[1];
                    v2 += (float)q23[0]; v3 += (float)q23[1];
                }
                acc[rt][nt][0] = v0; acc[rt][nt][1] = v1;
                acc[rt][nt][2] = v2; acc[rt][nt][3] = v3;
            }
            #pragma unroll
            for (int reg = 0; reg < 4; ++reg) {
                const int row_l = rt * 16 + lg * 4 + reg;
                const float* xr = x + (size_t)(r0 + row_l) * 64;
                float s_ = 0.f, q_ = 0.f;
                #pragma unroll
                for (int nt = 0; nt < 4; ++nt) {
                    float v = acc[rt][nt][reg] + xr[nt * 16 + lr];
                    rv[nt][reg] = v;
                    s_ += v;
                    q_ += v * v;
                }
                sum[reg] = s_;
                ssq[reg] = q_;
            }
            #pragma unroll
            for (int m = 1; m < 16; m <<= 1) {
                #pragma unroll
                for (int reg = 0; reg < 4; ++reg) {
                    sum[reg] += __shfl_xor(sum[reg], m, 64);
                    ssq[reg] += __shfl_xor(ssq[reg], m, 64);
                }
            }
            #pragma unroll
            for (int reg = 0; reg < 4; ++reg) {
                float mean = sum[reg] * (1.f / 64.f);
                float var = ssq[reg] * (1.f / 64.f) - mean * mean;
                float rstd = __frsqrt_rn(var + LN_EPS);
                const int gr = r0 + rt * 16 + lg * 4 + reg;
                #pragma unroll
                for (int nt = 0; nt < 4; ++nt) {
                    float y = (rv[nt][reg] - mean) * rstd * gba[nt] + bta[nt];
                    out[(size_t)gr * 64 + nt * 16 + lr] = y;
                }
            }
        }
    }
}

// ---------------------------------------------------------------------------
extern "C" void kernel_launch(void* const* d_in, const int* in_sizes, int n_in,
                              void* d_out, int out_size, void* d_ws, size_t ws_size,
                              hipStream_t stream) {
    const float* x     = (const float*)d_in[0];
    const float* W     = (const float*)d_in[1];
    const float* gamma = (const float*)d_in[2];
    const float* beta  = (const float*)d_in[3];
    float* outp        = (float*)d_out;

    char* ws = (char*)d_ws;
    _Float16* s_f16 = (_Float16*)ws;                                    // 4 MB
    _Float16* wt    = (_Float16*)(ws + (size_t)B_DIM * S_DIM * 64 * 2); // 512 KB

    prep_stage1<<<1536, 256, 0, stream>>>(x, W, wt, s_f16);
    stage2<<<(B_DIM * S_DIM) / 64, 256, 0, stream>>>(x, s_f16, wt, gamma, beta, outp);
}

// Round 10
// 34.607 us; speedup vs baseline: 1.3595x; 1.0915x over previous
//
#include <hip/hip_runtime.h>

#define S_DIM 4096
#define B_DIM 8
#define LN_EPS 1e-3f

typedef _Float16 half8 __attribute__((ext_vector_type(8)));
typedef _Float16 half2v __attribute__((ext_vector_type(2)));
typedef float f32x4 __attribute__((ext_vector_type(4)));

// ---------------------------------------------------------------------------
// Dispatch 1 (R5 skeleton): blocks 0..1023 = prep (fragment-contiguous wt2),
//   blocks 1024..1535 = banded stage1 (known-good 6-barrier version).
// wt2 layout: flat idx = ((a*8 + j)*64 + l)*8 + e  holds
//   W[k][a][c] with k=(j>>1)*16+(l&15), c=(j&1)*32+(l>>4)*8+e.
// A wave's per-slice fragment j is then 1KB contiguous, lane l <-> bytes l*16.
// ---------------------------------------------------------------------------
__global__ __launch_bounds__(256) void prep_stage1(const float* __restrict__ x,
                                                   const float* __restrict__ W,
                                                   _Float16* __restrict__ wt2,
                                                   _Float16* __restrict__ s_out) {
    if (blockIdx.x < 1024) {   // ---- prep role ----
        int idx = blockIdx.x * 256 + threadIdx.x;   // = a*4096 + j*512 + l*8 + e
        int a = idx >> 12;
        int j = (idx >> 9) & 7;
        int l2 = (idx >> 3) & 63;
        int e = idx & 7;
        int k = (j >> 1) * 16 + (l2 & 15);
        int c = (j & 1) * 32 + (l2 >> 4) * 8 + e;
        wt2[idx] = (_Float16)W[((k << 6) + a) * 64 + c];
        return;
    }
    // ---- stage1 role: banded s_pre (d <= 128..192), R5 version ----
    const int lin = blockIdx.x - 1024;
    const int it = lin & 63;
    const int by = lin >> 6;
    const int i0 = it * 64;
    const int tid = threadIdx.x;
    const int w = tid >> 6, l = tid & 63, lg = l >> 4, lr = l & 15;

    __shared__ _Float16 Bs[64 * 72];

    f32x4 acc[4] = {};
    const float iRowF = (float)(i0 + w * 16 + lr);
    const int ldC = tid & 63;
    const int ldJ = (tid >> 6) * 16;

    const int jt0 = (it >= 2) ? (it - 2) : 0;
    for (int jt = jt0; jt <= it; ++jt) {
        const int j0 = jt * 64;
        __syncthreads();
        {
            const float* xp = x + ((size_t)by * S_DIM + j0 + ldJ) * 64 + ldC;
            half8 v0, v1;
            #pragma unroll
            for (int q = 0; q < 8; ++q) {
                v0[q] = (_Float16)xp[q * 64];
                v1[q] = (_Float16)xp[(8 + q) * 64];
            }
            *(half8*)&Bs[ldC * 72 + ldJ] = v0;
            *(half8*)&Bs[ldC * 72 + ldJ + 8] = v1;
        }
        __syncthreads();
        #pragma unroll
        for (int kk = 0; kk < 2; ++kk) {
            half8 af;
            #pragma unroll
            for (int bq = 0; bq < 8; ++bq) {
                int j = j0 + kk * 32 + lg * 8 + bq;
                float df = iRowF - (float)j;
                float tv = (df > 0.f) ? __builtin_amdgcn_rcpf(df * df) : 0.f;
                af[bq] = (_Float16)tv;
            }
            #pragma unroll
            for (int nt = 0; nt < 4; ++nt) {
                half8 bf = *(const half8*)&Bs[(nt * 16 + lr) * 72 + kk * 32 + lg * 8];
                acc[nt] = __builtin_amdgcn_mfma_f32_16x16x32_f16(af, bf, acc[nt], 0, 0, 0);
            }
        }
    }

    #pragma unroll
    for (int nt = 0; nt < 4; ++nt)
        #pragma unroll
        for (int r = 0; r < 4; ++r)
            s_out[((size_t)by * S_DIM + i0 + w * 16 + lg * 4 + r) * 64 + nt * 16 + lr]
                = (_Float16)acc[nt][r];
}

// ---------------------------------------------------------------------------
// Stage 2 v8: NO LDS in the K-loop. 64 rows/block, 4 waves, K-split 4
//   (wave w: a = w*16+t). W fragments stream L2 -> VGPR from the
//   fragment-contiguous wt2 (1KB coalesced per load). SSA ping-pong
//   double buffer, one-cluster prefetch distance, compiler-managed vmcnt.
//   LDS: 24KB epilogue partial exchange only.
// ---------------------------------------------------------------------------
__global__ __launch_bounds__(256, 2) void stage2(const float* __restrict__ x,
                                                 const _Float16* __restrict__ s,
                                                 const _Float16* __restrict__ wt2,
                                                 const float* __restrict__ gamma,
                                                 const float* __restrict__ beta,
                                                 float* __restrict__ out) {
    const int r0 = blockIdx.x * 64;
    const int tid = threadIdx.x;
    const int w = tid >> 6, l = tid & 63, lg = l >> 4, lr = l & 15;

    __shared__ __align__(16) half2v Pf[6144];   // 24 KB epilogue partials

    // this wave's W stream: 16 slices x 8KB, lane-sliced by l*16
    const char* mylane = (const char*)wt2 + ((size_t)w << 17) + l * 16;

    // s fragments (A-operand base) and xa scalars
    half8 sf[4][2];
    #pragma unroll
    for (int rt = 0; rt < 4; ++rt) {
        size_t row = (size_t)(r0 + rt * 16 + lr) * 64;
        sf[rt][0] = *(const half8*)&s[row + lg * 8];
        sf[rt][1] = *(const half8*)&s[row + 32 + lg * 8];
    }
    half8 xav[4][2];
    #pragma unroll
    for (int rt = 0; rt < 4; ++rt) {
        const float* xp = x + (size_t)(r0 + rt * 16 + lr) * 64 + w * 16;
        half8 h0, h1;
        #pragma unroll
        for (int j = 0; j < 8; ++j) {
            h0[j] = (_Float16)xp[j];
            h1[j] = (_Float16)xp[8 + j];
        }
        xav[rt][0] = h0;
        xav[rt][1] = h1;
    }

    half8 bA[4][2], bB[4][2];   // [nt][c-half]; frag f = nt*2 + h

#define PREF(BUF, t_)                                                          \
    {                                                                          \
        _Pragma("unroll")                                                      \
        for (int f_ = 0; f_ < 8; ++f_)                                         \
            (&BUF[0][0])[f_] =                                                 \
                *(const half8*)(mylane + (size_t)(t_) * 8192 + f_ * 1024);     \
    }
#define CLUSTER(BUF, t_)                                                       \
    {                                                                          \
        _Pragma("unroll")                                                      \
        for (int rt_ = 0; rt_ < 4; ++rt_) {                                    \
            _Float16 xa = xav[rt_][(t_) >> 3][(t_) & 7];                       \
            half8 af0 = sf[rt_][0] * xa;                                       \
            half8 af1 = sf[rt_][1] * xa;                                       \
            _Pragma("unroll")                                                  \
            for (int nt_ = 0; nt_ < 4; ++nt_) {                                \
                acc[rt_][nt_] = __builtin_amdgcn_mfma_f32_16x16x32_f16(        \
                    af0, BUF[nt_][0], acc[rt_][nt_], 0, 0, 0);                 \
                acc[rt_][nt_] = __builtin_amdgcn_mfma_f32_16x16x32_f16(        \
                    af1, BUF[nt_][1], acc[rt_][nt_], 0, 0, 0);                 \
            }                                                                  \
        }                                                                      \
    }

    f32x4 acc[4][4] = {};
    PREF(bA, 0);
    #pragma unroll
    for (int tt = 0; tt < 8; ++tt) {
        const int t0 = tt * 2;
        PREF(bB, t0 + 1);          // in flight during cluster t0
        CLUSTER(bA, t0);
        if (t0 + 2 < 16) PREF(bA, t0 + 2);   // in flight during cluster t0+1
        CLUSTER(bB, t0 + 1);
    }
#undef PREF
#undef CLUSTER

    // ---- epilogue: waves 1..3 dump f16 partials, wave 0 combines + LN ----
    if (w != 0) {
        const int ph = w - 1;
        #pragma unroll
        for (int rt = 0; rt < 4; ++rt)
            #pragma unroll
            for (int nt = 0; nt < 4; ++nt) {
                int base = (((ph * 4 + rt) * 4 + nt) * 2) * 64 + l;
                half2v p01 = { (_Float16)acc[rt][nt][0], (_Float16)acc[rt][nt][1] };
                half2v p23 = { (_Float16)acc[rt][nt][2], (_Float16)acc[rt][nt][3] };
                Pf[base] = p01;
                Pf[base + 64] = p23;
            }
    }
    __syncthreads();

    if (w == 0) {
        float gba[4], bta[4];
        #pragma unroll
        for (int nt = 0; nt < 4; ++nt) {
            gba[nt] = gamma[nt * 16 + lr];
            bta[nt] = beta[nt * 16 + lr];
        }
        #pragma unroll
        for (int rt = 0; rt < 4; ++rt) {
            float rv[4][4], sum[4], ssq[4];
            #pragma unroll
            for (int nt = 0; nt < 4; ++nt) {
                float v0 = acc[rt][nt][0], v1 = acc[rt][nt][1];
                float v2 = acc[rt][nt][2], v3 = acc[rt][nt][3];
                #pragma unroll
                for (int ph = 0; ph < 3; ++ph) {
                    int base = (((ph * 4 + rt) * 4 + nt) * 2) * 64 + l;
                    half2v q01 = Pf[base];
                    half2v q23 = Pf[base + 64];
                    v0 += (float)q01[0]; v1 += (float)q01[1];
                    v2 += (float)q23[0]; v3 += (float)q23[1];
                }
                acc[rt][nt][0] = v0; acc[rt][nt][1] = v1;
                acc[rt][nt][2] = v2; acc[rt][nt][3] = v3;
            }
            #pragma unroll
            for (int reg = 0; reg < 4; ++reg) {
                const int row_l = rt * 16 + lg * 4 + reg;
                const float* xr = x + (size_t)(r0 + row_l) * 64;
                float s_ = 0.f, q_ = 0.f;
                #pragma unroll
                for (int nt = 0; nt < 4; ++nt) {
                    float v = acc[rt][nt][reg] + xr[nt * 16 + lr];
                    rv[nt][reg] = v;
                    s_ += v;
                    q_ += v * v;
                }
                sum[reg] = s_;
                ssq[reg] = q_;
            }
            #pragma unroll
            for (int m = 1; m < 16; m <<= 1) {
                #pragma unroll
                for (int reg = 0; reg < 4; ++reg) {
                    sum[reg] += __shfl_xor(sum[reg], m, 64);
                    ssq[reg] += __shfl_xor(ssq[reg], m, 64);
                }
            }
            #pragma unroll
            for (int reg = 0; reg < 4; ++reg) {
                float mean = sum[reg] * (1.f / 64.f);
                float var = ssq[reg] * (1.f / 64.f) - mean * mean;
                float rstd = __frsqrt_rn(var + LN_EPS);
                const int gr = r0 + rt * 16 + lg * 4 + reg;
                #pragma unroll
                for (int nt = 0; nt < 4; ++nt) {
                    float y = (rv[nt][reg] - mean) * rstd * gba[nt] + bta[nt];
                    out[(size_t)gr * 64 + nt * 16 + lr] = y;
                }
            }
        }
    }
}

// ---------------------------------------------------------------------------
extern "C" void kernel_launch(void* const* d_in, const int* in_sizes, int n_in,
                              void* d_out, int out_size, void* d_ws, size_t ws_size,
                              hipStream_t stream) {
    const float* x     = (const float*)d_in[0];
    const float* W     = (const float*)d_in[1];
    const float* gamma = (const float*)d_in[2];
    const float* beta  = (const float*)d_in[3];
    float* outp        = (float*)d_out;

    char* ws = (char*)d_ws;
    _Float16* s_f16 = (_Float16*)ws;                                    // 4 MB
    _Float16* wt2   = (_Float16*)(ws + (size_t)B_DIM * S_DIM * 64 * 2); // 512 KB

    prep_stage1<<<1536, 256, 0, stream>>>(x, W, wt2, s_f16);
    stage2<<<(B_DIM * S_DIM) / 64, 256, 0, stream>>>(x, s_f16, wt2, gamma, beta, outp);
}